// Round 4
// baseline (416.134 us; speedup 1.0000x reference)
//
#include <hip/hip_runtime.h>

// HistogramNd: values [N,3] f32, weights [N] f32 -> hist [64*64*64] f32 + oob scalar.
// d_out = [hist (out_size-1 floats), oob (1 float)].
//
// Strategy: per-XCD histogram replicas in d_ws. Atomics use WORKGROUP scope
// (__hip_atomic_fetch_add) -> global_atomic_add_f32 with no sc1 bit -> the RMW
// executes in the issuing XCD's own L2 (writeback-cached), not the memory-side
// write-through path that made rounds 1-2 emit 262 MB of scattered HBM writes.
// HW_REG_XCC_ID (HW-verified) selects the replica so only one XCD ever touches
// each copy; the end-of-dispatch release writes dirty L2 back before gather.

#define NREP 8

__device__ __forceinline__ unsigned xcd_id() {
    unsigned xcc;
    asm("s_getreg_b32 %0, hwreg(HW_REG_XCC_ID, 0, 4)" : "=s"(xcc));
    return xcc & (NREP - 1);
}

__device__ __forceinline__ void l2_atomic_add(float* p, float v) {
    // workgroup scope -> no sc1 -> XCD-local L2 atomic (writeback)
    __hip_atomic_fetch_add(p, v, __ATOMIC_RELAXED, __HIP_MEMORY_SCOPE_WORKGROUP);
}

__global__ void __launch_bounds__(256)
zero_ws_kernel(float4* __restrict__ ws4, int n4) {
    int i = blockIdx.x * blockDim.x + threadIdx.x;
    if (i < n4) ws4[i] = make_float4(0.f, 0.f, 0.f, 0.f);
}

__global__ void __launch_bounds__(256)
hist_rep_kernel(const float4* __restrict__ vals4,   // N*3/4 float4s
                const float4* __restrict__ w4,      // N/4 float4s
                const float* __restrict__ rmin,
                const float* __restrict__ rmax,
                const int* __restrict__ nbins,
                const int* __restrict__ stride,
                float* __restrict__ ws, int n4, int hist_n) {
    const unsigned xcc = xcd_id();
    float* __restrict__ rep = ws + (size_t)xcc * (size_t)hist_n;
    int i = blockIdx.x * blockDim.x + threadIdx.x;
    float oob = 0.f;
    if (i < n4) {
        const float lo0 = rmin[0], lo1 = rmin[1], lo2 = rmin[2];
        const float hi0 = rmax[0], hi1 = rmax[1], hi2 = rmax[2];
        const int   nb0 = nbins[0], nb1 = nbins[1], nb2 = nbins[2];
        const int   s0  = stride[0], s1 = stride[1], s2 = stride[2];

        const float4 a = vals4[3 * (long)i + 0];
        const float4 b = vals4[3 * (long)i + 1];
        const float4 c = vals4[3 * (long)i + 2];
        const float4 w = w4[i];

        const float px[4][3] = {{a.x, a.y, a.z},
                                {a.w, b.x, b.y},
                                {b.z, b.w, c.x},
                                {c.y, c.z, c.w}};
        const float wsv[4] = {w.x, w.y, w.z, w.w};

#pragma unroll
        for (int p = 0; p < 4; ++p) {
            const int b0 = (int)floorf((px[p][0] - lo0) / (hi0 - lo0) * (float)nb0);
            const int b1 = (int)floorf((px[p][1] - lo1) / (hi1 - lo1) * (float)nb1);
            const int b2 = (int)floorf((px[p][2] - lo2) / (hi2 - lo2) * (float)nb2);
            const bool valid = (b0 >= 0) & (b0 < nb0) &
                               (b1 >= 0) & (b1 < nb1) &
                               (b2 >= 0) & (b2 < nb2);
            if (valid) {
                l2_atomic_add(rep + (b0 * s0 + b1 * s1 + b2 * s2), wsv[p]);
            } else {
                oob += wsv[p];
            }
        }
    }
    // wave-level reduction of oob -> per-XCD oob slot (rarely nonzero)
#pragma unroll
    for (int o = 32; o > 0; o >>= 1) oob += __shfl_down(oob, o);
    if ((threadIdx.x & 63) == 0 && oob != 0.f)
        l2_atomic_add(ws + (size_t)NREP * (size_t)hist_n + xcc, oob);
}

__global__ void __launch_bounds__(256)
gather_kernel(const float* __restrict__ hist_sum,
              const float* __restrict__ oob_sum,
              const float* __restrict__ ws,
              float* __restrict__ out, int hist_n) {
    int i = blockIdx.x * blockDim.x + threadIdx.x;  // float4 index
    const int n4 = hist_n / 4;
    if (i < n4) {
        float4 acc = ((const float4*)hist_sum)[i];
#pragma unroll
        for (int r = 0; r < NREP; ++r) {
            const float4 t = ((const float4*)(ws + (size_t)r * (size_t)hist_n))[i];
            acc.x += t.x; acc.y += t.y; acc.z += t.z; acc.w += t.w;
        }
        ((float4*)out)[i] = acc;
    }
    if (i == 0) {
        float o = oob_sum[0];
#pragma unroll
        for (int r = 0; r < NREP; ++r) o += ws[(size_t)NREP * (size_t)hist_n + r];
        out[hist_n] = o;
    }
}

// ---- fallback path (round-2 kernels) if ws_size is too small ----
__global__ void __launch_bounds__(256)
init_out_kernel(const float* __restrict__ hist_sum,
                const float* __restrict__ oob_sum,
                float* __restrict__ out, int hist_n) {
    int i = blockIdx.x * blockDim.x + threadIdx.x;
    if (i < hist_n) out[i] = hist_sum[i];
    if (i == 0) out[hist_n] = oob_sum[0];
}

__global__ void __launch_bounds__(256)
hist_direct_kernel(const float4* __restrict__ vals4,
                   const float4* __restrict__ w4,
                   const float* __restrict__ rmin,
                   const float* __restrict__ rmax,
                   const int* __restrict__ nbins,
                   const int* __restrict__ stride,
                   float* __restrict__ out, int n4, int hist_n) {
    int i = blockIdx.x * blockDim.x + threadIdx.x;
    float oob = 0.f;
    if (i < n4) {
        const float lo0 = rmin[0], lo1 = rmin[1], lo2 = rmin[2];
        const float hi0 = rmax[0], hi1 = rmax[1], hi2 = rmax[2];
        const int   nb0 = nbins[0], nb1 = nbins[1], nb2 = nbins[2];
        const int   s0  = stride[0], s1 = stride[1], s2 = stride[2];
        const float4 a = vals4[3 * (long)i + 0];
        const float4 b = vals4[3 * (long)i + 1];
        const float4 c = vals4[3 * (long)i + 2];
        const float4 w = w4[i];
        const float px[4][3] = {{a.x, a.y, a.z}, {a.w, b.x, b.y},
                                {b.z, b.w, c.x}, {c.y, c.z, c.w}};
        const float wsv[4] = {w.x, w.y, w.z, w.w};
#pragma unroll
        for (int p = 0; p < 4; ++p) {
            const int b0 = (int)floorf((px[p][0] - lo0) / (hi0 - lo0) * (float)nb0);
            const int b1 = (int)floorf((px[p][1] - lo1) / (hi1 - lo1) * (float)nb1);
            const int b2 = (int)floorf((px[p][2] - lo2) / (hi2 - lo2) * (float)nb2);
            const bool valid = (b0 >= 0) & (b0 < nb0) & (b1 >= 0) & (b1 < nb1) &
                               (b2 >= 0) & (b2 < nb2);
            if (valid) unsafeAtomicAdd(&out[b0 * s0 + b1 * s1 + b2 * s2], wsv[p]);
            else       oob += wsv[p];
        }
    }
#pragma unroll
    for (int o = 32; o > 0; o >>= 1) oob += __shfl_down(oob, o);
    if ((threadIdx.x & 63) == 0 && oob != 0.f) unsafeAtomicAdd(&out[hist_n], oob);
}

extern "C" void kernel_launch(void* const* d_in, const int* in_sizes, int n_in,
                              void* d_out, int out_size, void* d_ws, size_t ws_size,
                              hipStream_t stream) {
    // input order: values, weights, hist_sum, oob_sum, range_min, range_max, n_bins, stride
    const float* values   = (const float*)d_in[0];
    const float* weights  = (const float*)d_in[1];
    const float* hist_sum = (const float*)d_in[2];
    const float* oob_sum  = (const float*)d_in[3];
    const float* rmin     = (const float*)d_in[4];
    const float* rmax     = (const float*)d_in[5];
    const int*   nbins    = (const int*)d_in[6];
    const int*   stride_p = (const int*)d_in[7];

    const int N      = in_sizes[1];      // number of points
    const int hist_n = out_size - 1;     // 64*64*64 = 262144
    const int n4     = N / 4;            // 4 points per thread
    const int threads = 256;

    const size_t ws_needed = ((size_t)NREP * (size_t)hist_n + NREP) * sizeof(float);

    if (ws_size >= ws_needed && (hist_n % 4) == 0) {
        // 1) zero replicas + oob slots
        const int zn4 = (int)((ws_needed + sizeof(float4) - 1) / sizeof(float4));
        zero_ws_kernel<<<(zn4 + threads - 1) / threads, threads, 0, stream>>>(
            (float4*)d_ws, zn4);
        // 2) scatter into per-XCD replicas via L2-local atomics
        hist_rep_kernel<<<(n4 + threads - 1) / threads, threads, 0, stream>>>(
            (const float4*)values, (const float4*)weights,
            rmin, rmax, nbins, stride_p, (float*)d_ws, n4, hist_n);
        // 3) gather replicas + hist_sum -> out
        const int g4 = hist_n / 4;
        gather_kernel<<<(g4 + threads - 1) / threads, threads, 0, stream>>>(
            hist_sum, oob_sum, (const float*)d_ws, (float*)d_out, hist_n);
    } else {
        init_out_kernel<<<(hist_n + 1 + threads - 1) / threads, threads, 0, stream>>>(
            hist_sum, oob_sum, (float*)d_out, hist_n);
        hist_direct_kernel<<<(n4 + threads - 1) / threads, threads, 0, stream>>>(
            (const float4*)values, (const float4*)weights,
            rmin, rmax, nbins, stride_p, (float*)d_out, n4, hist_n);
    }
}

// Round 6
// 200.298 us; speedup vs baseline: 2.0776x; 2.0776x over previous
//
#include <hip/hip_runtime.h>

// HistogramNd: values [N,3] f32, weights [N] f32 -> hist [64*64*64] f32 + oob.
// d_out = [hist (out_size-1 floats), oob (1 float)].
//
// Rounds 1-4 proved global fp32 atomics are memory-side on gfx950 at a hard
// ~20.7 G/s (identical 405 us, WRITE_SIZE=262MB for atomicAdd /
// unsafeAtomicAdd / workgroup-scope). Atomic-free design:
//   K1 bin_kernel:  values+weights -> packed {bin,w} records (no atomics).
//   K2 hist_pass:   16 bin-partitions x 32 data slices; each block scans one
//                   slice, ds_add_f32 into a 64KB static-LDS partial (16384
//                   bins), writes the partial densely. Slice readers share an
//                   XCD (s = bid%32, readers differ in bid by multiples of
//                   32 -> same bid%8) so re-reads hit the local L2.
//   K3 reduce:      out = hist_sum + sum of 32 partials per bin (+ oob).
// No dynamic LDS, no hipFuncSetAttribute, no inline asm (de-risked after two
// container crashes).

#define NPART 16
#define PBITS 14
#define PSIZE 16384          // bins per partition (64 KB static LDS)
#define B2    32             // data slices per partition

__global__ void __launch_bounds__(256)
bin_kernel(const float4* __restrict__ vals4,   // N*3/4 float4s
           const float4* __restrict__ w4,      // N/4 float4s
           const float* __restrict__ rmin,
           const float* __restrict__ rmax,
           const int* __restrict__ nbins,
           const int* __restrict__ stride,
           uint2* __restrict__ rec,            // N records {bin, w}
           float* __restrict__ oob_slot,
           int n4) {
    int i = blockIdx.x * blockDim.x + threadIdx.x;
    float oob = 0.f;
    if (i < n4) {
        const float lo0 = rmin[0], lo1 = rmin[1], lo2 = rmin[2];
        const float hi0 = rmax[0], hi1 = rmax[1], hi2 = rmax[2];
        const int   nb0 = nbins[0], nb1 = nbins[1], nb2 = nbins[2];
        const int   s0  = stride[0], s1 = stride[1], s2 = stride[2];

        const float4 a = vals4[3 * (long)i + 0];
        const float4 b = vals4[3 * (long)i + 1];
        const float4 c = vals4[3 * (long)i + 2];
        const float4 w = w4[i];

        const float px[4][3] = {{a.x, a.y, a.z},
                                {a.w, b.x, b.y},
                                {b.z, b.w, c.x},
                                {c.y, c.z, c.w}};
        const float wsv[4] = {w.x, w.y, w.z, w.w};

        unsigned bins[4];
#pragma unroll
        for (int p = 0; p < 4; ++p) {
            // exactly the reference math (same as the passing rounds 1-4)
            const int b0 = (int)floorf((px[p][0] - lo0) / (hi0 - lo0) * (float)nb0);
            const int b1 = (int)floorf((px[p][1] - lo1) / (hi1 - lo1) * (float)nb1);
            const int b2 = (int)floorf((px[p][2] - lo2) / (hi2 - lo2) * (float)nb2);
            const bool valid = (b0 >= 0) & (b0 < nb0) &
                               (b1 >= 0) & (b1 < nb1) &
                               (b2 >= 0) & (b2 < nb2);
            if (valid) {
                bins[p] = (unsigned)(b0 * s0 + b1 * s1 + b2 * s2);
            } else {
                bins[p] = 0xFFFFFFFFu;   // sentinel: matches no partition
                oob += wsv[p];
            }
        }
        uint4* dst = (uint4*)(rec + 4 * (long)i);  // 32B/thread, contiguous
        dst[0] = make_uint4(bins[0], __float_as_uint(wsv[0]),
                            bins[1], __float_as_uint(wsv[1]));
        dst[1] = make_uint4(bins[2], __float_as_uint(wsv[2]),
                            bins[3], __float_as_uint(wsv[3]));
    }
    // rare OOB: wave-reduce, at most one device atomic per wave
#pragma unroll
    for (int o = 32; o > 0; o >>= 1) oob += __shfl_down(oob, o);
    if ((threadIdx.x & 63) == 0 && oob != 0.f) unsafeAtomicAdd(oob_slot, oob);
}

__global__ void __launch_bounds__(512)
hist_pass_kernel(const uint2* __restrict__ rec,
                 float* __restrict__ part,     // [NPART*B2][PSIZE]
                 int n_rec) {
    __shared__ float lh[PSIZE];                // 64 KB static LDS
    const int p = blockIdx.x / B2;             // bin partition 0..15
    const int s = blockIdx.x % B2;             // data slice 0..31 (same-XCD readers)
    for (int k = threadIdx.x; k < PSIZE; k += 512) lh[k] = 0.f;
    __syncthreads();

    const int per = n_rec / B2;                // records per slice
    const uint4* b4 = (const uint4*)(rec + (size_t)s * per);  // 2 records/load
    const unsigned lo = (unsigned)p << PBITS;
    for (int k = threadIdx.x; k < per / 2; k += 512) {
        const uint4 q = b4[k];
        if ((q.x >> PBITS) == (unsigned)p)
            atomicAdd(&lh[q.x - lo], __uint_as_float(q.y));   // ds_add_f32
        if ((q.z >> PBITS) == (unsigned)p)
            atomicAdd(&lh[q.z - lo], __uint_as_float(q.w));
    }
    __syncthreads();

    float4* dst = (float4*)(part + (size_t)blockIdx.x * PSIZE);
    const float4* src = (const float4*)lh;
    for (int k = threadIdx.x; k < PSIZE / 4; k += 512) dst[k] = src[k];
}

__global__ void __launch_bounds__(256)
reduce_kernel(const float* __restrict__ hist_sum,
              const float* __restrict__ oob_sum,
              const float* __restrict__ part,
              const float* __restrict__ oob_slot,
              float* __restrict__ out, int hist_n) {
    int i = blockIdx.x * blockDim.x + threadIdx.x;   // float4 index
    const int n4 = hist_n / 4;
    if (i < n4) {
        float4 acc = ((const float4*)hist_sum)[i];
        const int p = i >> (PBITS - 2);              // partition of bin 4i
        const int local4 = i - (p << (PBITS - 2));
        const float4* pp = (const float4*)(part + (size_t)p * B2 * PSIZE) + local4;
#pragma unroll 4
        for (int s = 0; s < B2; ++s) {
            const float4 t = pp[(size_t)s * (PSIZE / 4)];
            acc.x += t.x; acc.y += t.y; acc.z += t.z; acc.w += t.w;
        }
        ((float4*)out)[i] = acc;
    }
    if (i == 0) out[hist_n] = oob_sum[0] + oob_slot[0];
}

// ---- fallback path (round-1 kernels, known-passing at ~405 us) ----
__global__ void __launch_bounds__(256)
init_out_kernel(const float* __restrict__ hist_sum,
                const float* __restrict__ oob_sum,
                float* __restrict__ out, int hist_n) {
    int i = blockIdx.x * blockDim.x + threadIdx.x;
    if (i < hist_n) out[i] = hist_sum[i];
    if (i == 0) out[hist_n] = oob_sum[0];
}

__global__ void __launch_bounds__(256)
hist_direct_kernel(const float4* __restrict__ vals4,
                   const float4* __restrict__ w4,
                   const float* __restrict__ rmin,
                   const float* __restrict__ rmax,
                   const int* __restrict__ nbins,
                   const int* __restrict__ stride,
                   float* __restrict__ out, int n4, int hist_n) {
    int i = blockIdx.x * blockDim.x + threadIdx.x;
    float oob = 0.f;
    if (i < n4) {
        const float lo0 = rmin[0], lo1 = rmin[1], lo2 = rmin[2];
        const float hi0 = rmax[0], hi1 = rmax[1], hi2 = rmax[2];
        const int   nb0 = nbins[0], nb1 = nbins[1], nb2 = nbins[2];
        const int   s0  = stride[0], s1 = stride[1], s2 = stride[2];
        const float4 a = vals4[3 * (long)i + 0];
        const float4 b = vals4[3 * (long)i + 1];
        const float4 c = vals4[3 * (long)i + 2];
        const float4 w = w4[i];
        const float px[4][3] = {{a.x, a.y, a.z}, {a.w, b.x, b.y},
                                {b.z, b.w, c.x}, {c.y, c.z, c.w}};
        const float wsv[4] = {w.x, w.y, w.z, w.w};
#pragma unroll
        for (int p = 0; p < 4; ++p) {
            const int b0 = (int)floorf((px[p][0] - lo0) / (hi0 - lo0) * (float)nb0);
            const int b1 = (int)floorf((px[p][1] - lo1) / (hi1 - lo1) * (float)nb1);
            const int b2 = (int)floorf((px[p][2] - lo2) / (hi2 - lo2) * (float)nb2);
            const bool valid = (b0 >= 0) & (b0 < nb0) & (b1 >= 0) & (b1 < nb1) &
                               (b2 >= 0) & (b2 < nb2);
            if (valid) unsafeAtomicAdd(&out[b0 * s0 + b1 * s1 + b2 * s2], wsv[p]);
            else       oob += wsv[p];
        }
    }
#pragma unroll
    for (int o = 32; o > 0; o >>= 1) oob += __shfl_down(oob, o);
    if ((threadIdx.x & 63) == 0 && oob != 0.f) unsafeAtomicAdd(&out[hist_n], oob);
}

extern "C" void kernel_launch(void* const* d_in, const int* in_sizes, int n_in,
                              void* d_out, int out_size, void* d_ws, size_t ws_size,
                              hipStream_t stream) {
    // inputs: values, weights, hist_sum, oob_sum, range_min, range_max, n_bins, stride
    const float* values   = (const float*)d_in[0];
    const float* weights  = (const float*)d_in[1];
    const float* hist_sum = (const float*)d_in[2];
    const float* oob_sum  = (const float*)d_in[3];
    const float* rmin     = (const float*)d_in[4];
    const float* rmax     = (const float*)d_in[5];
    const int*   nbins    = (const int*)d_in[6];
    const int*   stride_p = (const int*)d_in[7];

    const int N      = in_sizes[1];
    const int hist_n = out_size - 1;          // 262144
    const int n4     = N / 4;

    // ws layout: records (N*8B) | partials (NPART*B2*PSIZE*4B) | oob slot
    const size_t rec_bytes  = (size_t)N * 8;
    const size_t part_off   = rec_bytes;
    const size_t part_bytes = (size_t)NPART * B2 * PSIZE * 4;
    const size_t oob_off    = part_off + part_bytes;
    const size_t ws_needed  = oob_off + 16;

    const bool fast = (ws_size >= ws_needed) &&
                      (hist_n == NPART * PSIZE) &&
                      (N % (B2 * 2) == 0) && (N % 1024 == 0);

    if (fast) {
        uint2* rec   = (uint2*)d_ws;
        float* part  = (float*)((char*)d_ws + part_off);
        float* oobsl = (float*)((char*)d_ws + oob_off);

        hipMemsetAsync(oobsl, 0, sizeof(float), stream);

        bin_kernel<<<n4 / 256, 256, 0, stream>>>(
            (const float4*)values, (const float4*)weights,
            rmin, rmax, nbins, stride_p, rec, oobsl, n4);

        hist_pass_kernel<<<NPART * B2, 512, 0, stream>>>(rec, part, N);

        reduce_kernel<<<(hist_n / 4 + 255) / 256, 256, 0, stream>>>(
            hist_sum, oob_sum, part, oobsl, (float*)d_out, hist_n);
    } else {
        init_out_kernel<<<(hist_n + 256) / 256, 256, 0, stream>>>(
            hist_sum, oob_sum, (float*)d_out, hist_n);
        hist_direct_kernel<<<(n4 + 255) / 256, 256, 0, stream>>>(
            (const float4*)values, (const float4*)weights,
            rmin, rmax, nbins, stride_p, (float*)d_out, n4, hist_n);
    }
}

// Round 8
// 120.019 us; speedup vs baseline: 3.4672x; 1.6689x over previous
//
#include <hip/hip_runtime.h>

// HistogramNd: values [N,3] f32, weights [N] f32 -> hist [64*64*64] f32 + oob.
// d_out = [hist (out_size-1 floats), oob (1 float)].
//
// History: global fp32 atomics are memory-side @ ~20.7 G/s regardless of scope
// (rounds 1-4, identical 405us / WRITE=262MB). Round 6 (records + 16x re-read
// partitioned LDS histogram) = 200us, bottleneck hist_pass 159us: 1.07 GB of
// record re-reads served by L3 at ~6.7 TB/s (per-XCD L2 thrashes: 4 slices x
// 2.1MB > 4MB). This round: single-read bucketing. K1 scatters records into 16
// per-partition global buckets (LDS-staged, coalesced chunk copy). K2 reads
// each bucket once into a 64KB LDS partial (16 slices/partition). K3 reduces.
// (Round 7 never ran — container died before first message; resubmitted as-is.)

#define NPART 16
#define PBITS 14
#define PSIZE 16384          // bins per partition (64 KB LDS)
#define NSLICE 16            // K2 blocks per partition
#define STAGE_CAP 256        // per-partition staging slots in K1 (2048 recs/block)

__global__ void __launch_bounds__(512)
bucket_kernel(const float4* __restrict__ vals4,   // N*3/4 float4s
              const float4* __restrict__ w4,      // N/4 float4s
              const float* __restrict__ rmin,
              const float* __restrict__ rmax,
              const int* __restrict__ nbins,
              const int* __restrict__ stride,
              uint2* __restrict__ buckets,        // [NPART][cap]
              unsigned cap,
              unsigned* __restrict__ cursor,      // [NPART], pre-zeroed
              float* __restrict__ oob_slot,       // pre-zeroed
              int n4) {
    __shared__ uint2    stage[NPART * STAGE_CAP];  // 32 KB
    __shared__ unsigned lcur[NPART];
    __shared__ unsigned gbase[NPART];
    __shared__ unsigned lcnt[NPART];

    const int t = threadIdx.x;
    if (t < NPART) lcur[t] = 0u;
    __syncthreads();

    const int i = blockIdx.x * 512 + t;
    float oob = 0.f;
    unsigned bins[4];
    float    wv[4];
    bool     vld[4] = {false, false, false, false};

    if (i < n4) {
        const float lo0 = rmin[0], lo1 = rmin[1], lo2 = rmin[2];
        const float hi0 = rmax[0], hi1 = rmax[1], hi2 = rmax[2];
        const int   nb0 = nbins[0], nb1 = nbins[1], nb2 = nbins[2];
        const int   s0  = stride[0], s1 = stride[1], s2 = stride[2];

        const float4 a = vals4[3 * (long)i + 0];
        const float4 b = vals4[3 * (long)i + 1];
        const float4 c = vals4[3 * (long)i + 2];
        const float4 w = w4[i];

        const float px[4][3] = {{a.x, a.y, a.z},
                                {a.w, b.x, b.y},
                                {b.z, b.w, c.x},
                                {c.y, c.z, c.w}};
        const float wsv[4] = {w.x, w.y, w.z, w.w};

#pragma unroll
        for (int r = 0; r < 4; ++r) {
            // exactly the reference math (same as passing rounds 1-6)
            const int b0 = (int)floorf((px[r][0] - lo0) / (hi0 - lo0) * (float)nb0);
            const int b1 = (int)floorf((px[r][1] - lo1) / (hi1 - lo1) * (float)nb1);
            const int b2 = (int)floorf((px[r][2] - lo2) / (hi2 - lo2) * (float)nb2);
            const bool valid = (b0 >= 0) & (b0 < nb0) &
                               (b1 >= 0) & (b1 < nb1) &
                               (b2 >= 0) & (b2 < nb2);
            if (valid) {
                bins[r] = (unsigned)(b0 * s0 + b1 * s1 + b2 * s2);
                wv[r]   = wsv[r];
                vld[r]  = true;
            } else {
                oob += wsv[r];
            }
        }
    }

    // single-phase LDS scatter: fixed 256-slot region per partition
#pragma unroll
    for (int r = 0; r < 4; ++r) {
        if (vld[r]) {
            const unsigned p   = bins[r] >> PBITS;
            const unsigned pos = atomicAdd(&lcur[p], 1u);
            const uint2 recv   = make_uint2(bins[r], __float_as_uint(wv[r]));
            if (pos < (unsigned)STAGE_CAP) {
                stage[(p << 8) + pos] = recv;
            } else {
                // ~11-sigma overflow: direct global reservation (correct, rare)
                const unsigned g = atomicAdd(&cursor[p], 1u);
                if (g < cap) buckets[(size_t)p * cap + g] = recv;
            }
        }
    }
    __syncthreads();

    if (t < NPART) {
        const unsigned c = min(lcur[t], (unsigned)STAGE_CAP);
        lcnt[t]  = c;
        gbase[t] = atomicAdd(&cursor[t], c);   // one device atomic per partition per block
    }
    __syncthreads();

    // cooperative coalesced copy: per-partition contiguous chunks
    for (int idx = t; idx < NPART * STAGE_CAP; idx += 512) {
        const unsigned p   = (unsigned)idx >> 8;
        const unsigned off = (unsigned)idx & (STAGE_CAP - 1);
        if (off < lcnt[p]) {
            const unsigned g = gbase[p] + off;
            if (g < cap) buckets[(size_t)p * cap + g] = stage[idx];
        }
    }

    // rare OOB: wave-reduce, at most one device atomic per wave
#pragma unroll
    for (int o = 32; o > 0; o >>= 1) oob += __shfl_down(oob, o);
    if ((t & 63) == 0 && oob != 0.f) unsafeAtomicAdd(oob_slot, oob);
}

__global__ void __launch_bounds__(512)
hist_bucket_kernel(const uint2* __restrict__ buckets, unsigned cap,
                   const unsigned* __restrict__ cursor,
                   float* __restrict__ part) {      // [NPART*NSLICE][PSIZE]
    __shared__ float lh[PSIZE];                     // 64 KB
    const int p = blockIdx.x >> 4;                  // partition
    const int k = blockIdx.x & (NSLICE - 1);        // slice
    for (int j = threadIdx.x; j < PSIZE; j += 512) lh[j] = 0.f;
    __syncthreads();

    const unsigned cnt   = min(cursor[p], cap);
    const unsigned per   = (cnt + NSLICE - 1) / NSLICE;
    const unsigned start = (unsigned)k * per;
    const unsigned end   = min(start + per, cnt);
    const uint2* b = buckets + (size_t)p * cap;
    const unsigned lo = (unsigned)p << PBITS;

    for (unsigned j = start + threadIdx.x; j < end; j += 512) {
        const uint2 r = b[j];
        if ((r.x >> PBITS) == (unsigned)p)          // guard against stray records
            atomicAdd(&lh[r.x - lo], __uint_as_float(r.y));   // ds_add_f32
    }
    __syncthreads();

    float4* dst = (float4*)(part + (size_t)blockIdx.x * PSIZE);
    const float4* src = (const float4*)lh;
    for (int j = threadIdx.x; j < PSIZE / 4; j += 512) dst[j] = src[j];
}

__global__ void __launch_bounds__(256)
reduce_kernel(const float* __restrict__ hist_sum,
              const float* __restrict__ oob_sum,
              const float* __restrict__ part,
              const float* __restrict__ oob_slot,
              float* __restrict__ out, int hist_n) {
    int i = blockIdx.x * blockDim.x + threadIdx.x;   // float4 index
    const int n4 = hist_n / 4;
    if (i < n4) {
        float4 acc = ((const float4*)hist_sum)[i];
        const int p = i >> (PBITS - 2);              // partition of bin 4i
        const int local4 = i & ((1 << (PBITS - 2)) - 1);
        const float4* pp = (const float4*)(part + (size_t)p * NSLICE * PSIZE) + local4;
#pragma unroll 4
        for (int s = 0; s < NSLICE; ++s) {
            const float4 tv = pp[(size_t)s * (PSIZE / 4)];
            acc.x += tv.x; acc.y += tv.y; acc.z += tv.z; acc.w += tv.w;
        }
        ((float4*)out)[i] = acc;
    }
    if (i == 0) out[hist_n] = oob_sum[0] + oob_slot[0];
}

// ---- fallback path (round-1 kernels, known-passing at ~405 us) ----
__global__ void __launch_bounds__(256)
init_out_kernel(const float* __restrict__ hist_sum,
                const float* __restrict__ oob_sum,
                float* __restrict__ out, int hist_n) {
    int i = blockIdx.x * blockDim.x + threadIdx.x;
    if (i < hist_n) out[i] = hist_sum[i];
    if (i == 0) out[hist_n] = oob_sum[0];
}

__global__ void __launch_bounds__(256)
hist_direct_kernel(const float4* __restrict__ vals4,
                   const float4* __restrict__ w4,
                   const float* __restrict__ rmin,
                   const float* __restrict__ rmax,
                   const int* __restrict__ nbins,
                   const int* __restrict__ stride,
                   float* __restrict__ out, int n4, int hist_n) {
    int i = blockIdx.x * blockDim.x + threadIdx.x;
    float oob = 0.f;
    if (i < n4) {
        const float lo0 = rmin[0], lo1 = rmin[1], lo2 = rmin[2];
        const float hi0 = rmax[0], hi1 = rmax[1], hi2 = rmax[2];
        const int   nb0 = nbins[0], nb1 = nbins[1], nb2 = nbins[2];
        const int   s0  = stride[0], s1 = stride[1], s2 = stride[2];
        const float4 a = vals4[3 * (long)i + 0];
        const float4 b = vals4[3 * (long)i + 1];
        const float4 c = vals4[3 * (long)i + 2];
        const float4 w = w4[i];
        const float px[4][3] = {{a.x, a.y, a.z}, {a.w, b.x, b.y},
                                {b.z, b.w, c.x}, {c.y, c.z, c.w}};
        const float wsv[4] = {w.x, w.y, w.z, w.w};
#pragma unroll
        for (int p = 0; p < 4; ++p) {
            const int b0 = (int)floorf((px[p][0] - lo0) / (hi0 - lo0) * (float)nb0);
            const int b1 = (int)floorf((px[p][1] - lo1) / (hi1 - lo1) * (float)nb1);
            const int b2 = (int)floorf((px[p][2] - lo2) / (hi2 - lo2) * (float)nb2);
            const bool valid = (b0 >= 0) & (b0 < nb0) & (b1 >= 0) & (b1 < nb1) &
                               (b2 >= 0) & (b2 < nb2);
            if (valid) unsafeAtomicAdd(&out[b0 * s0 + b1 * s1 + b2 * s2], wsv[p]);
            else       oob += wsv[p];
        }
    }
#pragma unroll
    for (int o = 32; o > 0; o >>= 1) oob += __shfl_down(oob, o);
    if ((threadIdx.x & 63) == 0 && oob != 0.f) unsafeAtomicAdd(&out[hist_n], oob);
}

extern "C" void kernel_launch(void* const* d_in, const int* in_sizes, int n_in,
                              void* d_out, int out_size, void* d_ws, size_t ws_size,
                              hipStream_t stream) {
    // inputs: values, weights, hist_sum, oob_sum, range_min, range_max, n_bins, stride
    const float* values   = (const float*)d_in[0];
    const float* weights  = (const float*)d_in[1];
    const float* hist_sum = (const float*)d_in[2];
    const float* oob_sum  = (const float*)d_in[3];
    const float* rmin     = (const float*)d_in[4];
    const float* rmax     = (const float*)d_in[5];
    const int*   nbins    = (const int*)d_in[6];
    const int*   stride_p = (const int*)d_in[7];

    const int N      = in_sizes[1];
    const int hist_n = out_size - 1;          // 262144
    const int n4     = N / 4;

    // bucket capacity: N/16 + N/128 slack (~90 sigma for uniform data)
    const unsigned cap = (unsigned)(N / NPART + N / 128);

    // ws layout: buckets | partials | cursor[16] | oob slot
    const size_t buck_bytes = (size_t)NPART * cap * 8;
    const size_t part_off   = buck_bytes;
    const size_t part_bytes = (size_t)NPART * NSLICE * PSIZE * 4;
    const size_t cur_off    = part_off + part_bytes;
    const size_t oob_off    = cur_off + NPART * 4;
    const size_t ws_needed  = oob_off + 16;

    const bool fast = (ws_size >= ws_needed) &&
                      (hist_n == NPART * PSIZE) &&
                      (N % 4 == 0);

    if (fast) {
        uint2*    buckets = (uint2*)d_ws;
        float*    part    = (float*)((char*)d_ws + part_off);
        unsigned* cursor  = (unsigned*)((char*)d_ws + cur_off);
        float*    oobsl   = (float*)((char*)d_ws + oob_off);

        // zero cursors + oob slot (graph-capture-safe, proven in round 6)
        hipMemsetAsync(cursor, 0, NPART * 4 + 16, stream);

        const int k1_blocks = (n4 + 511) / 512;
        bucket_kernel<<<k1_blocks, 512, 0, stream>>>(
            (const float4*)values, (const float4*)weights,
            rmin, rmax, nbins, stride_p,
            buckets, cap, cursor, oobsl, n4);

        hist_bucket_kernel<<<NPART * NSLICE, 512, 0, stream>>>(
            buckets, cap, cursor, part);

        reduce_kernel<<<(hist_n / 4 + 255) / 256, 256, 0, stream>>>(
            hist_sum, oob_sum, part, oobsl, (float*)d_out, hist_n);
    } else {
        init_out_kernel<<<(hist_n + 256) / 256, 256, 0, stream>>>(
            hist_sum, oob_sum, (float*)d_out, hist_n);
        hist_direct_kernel<<<(n4 + 255) / 256, 256, 0, stream>>>(
            (const float4*)values, (const float4*)weights,
            rmin, rmax, nbins, stride_p, (float*)d_out, n4, hist_n);
    }
}